// Round 9
// baseline (239.847 us; speedup 1.0000x reference)
//
#include <hip/hip_runtime.h>
#include <math.h>

#define BB 4
#define CC 256
#define HH 64
#define WW 64
#define KP 9
#define GG 32
#define HWW (HH*WW)                 // 4096
#define FEL ((size_t)BB*CC*HH*WW)   // 4194304
#define GN_CNT 32768.0f             // (CC/GG)*H*W

typedef __bf16 bf16x8 __attribute__((ext_vector_type(8)));
typedef float  f32x4  __attribute__((ext_vector_type(4)));
typedef float  f32x2  __attribute__((ext_vector_type(2)));

__device__ __forceinline__ float bflo(unsigned u) {
    union { unsigned u; float f; } x; x.u = u << 16; return x.f;
}
__device__ __forceinline__ float bfhi(unsigned u) {
    union { unsigned u; float f; } x; x.u = u & 0xffff0000u; return x.f;
}
__device__ __forceinline__ f32x2 up2(unsigned u) {
    return (f32x2){bflo(u), bfhi(u)};
}

// XOR-swizzled LDS addressing, 256-element (512 B) rows; P = 16B chunk 0..31:
#define VT256_RD(row, P)  (((row) << 8) + ((((P) ^ ((row) & 7))) << 3))
// 128-element (256 B) rows (deform half-channel buffers), P = 16B chunk 0..15:
#define VT128_RD(row, P)  (((row) << 7) + ((((P) ^ ((row) & 7))) << 3))

// ---------------------------------------------------------------------------
// Fused: NCHW fp32 -> NHWC bf16 transpose (blocks 0..2047) + all weight-frag
// prep + stats zeroing (blocks 2048..9247).
__global__ void prep_and_transpose(
    const float* __restrict__ cls, const float* __restrict__ reg,
    __bf16* __restrict__ out_cls, __bf16* __restrict__ out_reg,
    const float* __restrict__ w1, const float* __restrict__ wc,
    const float* __restrict__ wr, const float* __restrict__ w18,
    __bf16* __restrict__ f1, __bf16* __restrict__ fc,
    __bf16* __restrict__ fr, __bf16* __restrict__ f18,
    float* __restrict__ stats)
{
    int blk = blockIdx.x;
    if (blk < 2048) {
        __shared__ float tile[64][65];
        int c0 = (blk & 3) * 64;
        int y  = (blk >> 2) & 63;
        int z  = blk >> 8;
        int b  = z & 3;
        const float* in = (z >> 2) ? reg : cls;
        __bf16* out     = (z >> 2) ? out_reg : out_cls;
        int lx = threadIdx.x & 63;
        int q  = threadIdx.x >> 6;
        for (int j = 0; j < 16; ++j) {
            int ci = q * 16 + j;
            tile[ci][lx] = in[(((size_t)b*CC + c0 + ci)*HH + y)*WW + lx];
        }
        __syncthreads();
        for (int j = 0; j < 16; ++j) {
            int xi = q * 16 + j;
            out[(((size_t)b*HH + y)*WW + xi)*CC + c0 + lx] = (__bf16)tile[lx][xi];
        }
        return;
    }
    int gid = (blk - 2048) * 256 + threadIdx.x;
    if (gid < 768) stats[gid] = 0.f;
    const int NW = 589824;
    if (gid < 3 * NW) {
        int which = gid / NW;
        int idx = gid - which * NW;
        int j   = idx & 7;
        int l   = (idx >> 3) & 63;
        int o16 = (idx >> 9) & 15;
        int c0  = (idx >> 13) & 7;
        int k   = idx >> 16;
        int o = o16 * 16 + (l & 15);
        int c = c0 * 32 + (l >> 4) * 8 + j;
        const float* src = (which == 0) ? w1 : ((which == 1) ? wc : wr);
        __bf16* dst = (which == 0) ? f1 : ((which == 1) ? fc : fr);
        dst[idx] = (__bf16)src[(size_t)(o * 256 + c) * 9 + k];
    } else {
        int idx = gid - 3 * NW;   // < 73728
        int j   = idx & 7;
        int l   = (idx >> 3) & 63;
        int o16 = (idx >> 9) & 1;
        int c0  = (idx >> 10) & 7;
        int k   = idx >> 13;
        int o = o16 * 16 + (l & 15);
        int c = c0 * 32 + (l >> 4) * 8 + j;
        float v = (o < 18) ? w18[(size_t)(o * 256 + c) * 9 + k] : 0.f;
        f18[idx] = (__bf16)v;
    }
}

// ---------------------------------------------------------------------------
// conv3x3 C256->C256 via bf16 MFMA. Block = 64 px x 256 o, 512 threads (8 waves,
// wave w owns o16 pair w*2, w*2+1): 4 A-reads + 2 B-loads -> 8 MFMAs (2/ds_read).
// Weights read ONCE per block. grid 256: blk&3=b, y=blk>>2.
__global__ __launch_bounds__(512, 2) void conv1_mfma(
    const __bf16* __restrict__ in_cl,   // [B,H,W,256] bf16
    const __bf16* __restrict__ wf,      // frag [9][8][16][64][8]
    const float* __restrict__ bias,
    __bf16* __restrict__ t_out,         // [B,H,W,256] bf16 (pre-GN)
    float* __restrict__ stats)
{
    __shared__ __bf16 Vt[66 * 256];
    __shared__ float groupStats[64];
    int blk = blockIdx.x;
    int bb = blk & 3;
    int y  = blk >> 2;
    int t  = threadIdx.x;
    int w  = t >> 6;            // 0..7
    int l  = t & 63;
    int quad = l >> 4;
    int l15  = l & 15;
    if (t < 64) groupStats[t] = 0.f;

    const __bf16* inb = in_cl + (size_t)bb * HWW * CC;
    f32x4 acc[4][2];   // [pt][ot]
    #pragma unroll
    for (int i = 0; i < 4; ++i)
        #pragma unroll
        for (int j = 0; j < 2; ++j)
            acc[i][j] = (f32x4){0.f, 0.f, 0.f, 0.f};

    for (int ky = 0; ky < 3; ++ky) {
        int yy = y + ky - 1;
        bool yok = (yy >= 0 && yy < HH);
        __syncthreads();
        for (int u = t; u < 66 * 32; u += 512) {
            int xl = u >> 5, cu = u & 31;
            int gx = xl - 1;
            uint4 val = make_uint4(0u, 0u, 0u, 0u);
            if (yok && gx >= 0 && gx < WW)
                val = *(const uint4*)(inb + ((size_t)(yy * WW + gx)) * CC + cu * 8);
            *(uint4*)&Vt[VT256_RD(xl, cu)] = val;
        }
        __syncthreads();
        #pragma unroll
        for (int kx = 0; kx < 3; ++kx) {
            int k = ky * 3 + kx;
            const bf16x8* wbase = (const bf16x8*)(wf + (size_t)k * 65536);
            for (int c0 = 0; c0 < 8; ++c0) {
                bf16x8 a[4], bfr[2];
                #pragma unroll
                for (int pt = 0; pt < 4; ++pt) {
                    int row = pt * 16 + l15 + kx;
                    a[pt] = *(const bf16x8*)&Vt[VT256_RD(row, c0 * 4 + quad)];
                }
                #pragma unroll
                for (int ot = 0; ot < 2; ++ot)
                    bfr[ot] = wbase[(c0 * 16 + (w * 2 + ot)) * 64 + l];
                #pragma unroll
                for (int pt = 0; pt < 4; ++pt)
                    #pragma unroll
                    for (int ot = 0; ot < 2; ++ot)
                        acc[pt][ot] = __builtin_amdgcn_mfma_f32_16x16x32_bf16(
                            a[pt], bfr[ot], acc[pt][ot], 0, 0, 0);
            }
        }
    }
    // D[m=px][n=o]; px = pt*16 + quad*4 + r; o = w*32 + ot*16 + l15
    #pragma unroll
    for (int ot = 0; ot < 2; ++ot) {
        int o = w * 32 + ot * 16 + l15;
        float bi = bias[o];
        float s1 = 0.f, s2 = 0.f;
        #pragma unroll
        for (int pt = 0; pt < 4; ++pt)
            #pragma unroll
            for (int r = 0; r < 4; ++r) {
                float v = acc[pt][ot][r] + bi;
                int px = pt * 16 + quad * 4 + r;
                t_out[(((size_t)bb * HH + y) * WW + px) * CC + o] = (__bf16)v;
                s1 += v; s2 += v * v;
            }
        s1 += __shfl_xor(s1, 16, 64); s1 += __shfl_xor(s1, 32, 64);
        s2 += __shfl_xor(s2, 16, 64); s2 += __shfl_xor(s2, 32, 64);
        if (quad == 0) {
            atomicAdd(&groupStats[(o >> 3) * 2],     s1);
            atomicAdd(&groupStats[(o >> 3) * 2 + 1], s2);
        }
    }
    __syncthreads();
    if (t < 64) atomicAdd(&stats[bb * 64 + t], groupStats[t]);
}

// ---------------------------------------------------------------------------
// Offset head conv3x3 C256->18 via bf16 MFMA, GN+ReLU fused into 16B staging.
// Half-row split: grid 512, blk&3=b, (blk>>2)&1=xh, y=blk>>3.
__global__ __launch_bounds__(256, 4) void conv18_mfma(
    const __bf16* __restrict__ t_bf,    // [B,H,W,256] bf16 raw (pre-GN)
    const __bf16* __restrict__ wf18,    // frag [9][8][2][64][8]
    const float* __restrict__ bias,     // [18]
    const float* __restrict__ stats,    // conv1 GN stats, + b*64
    const float* __restrict__ gamma, const float* __restrict__ beta,
    float* __restrict__ pts)            // [B,18,H,W]
{
    __shared__ __bf16 Vt[34 * 256];
    int blk = blockIdx.x;
    int bb = blk & 3;
    int xh = (blk >> 2) & 1;
    int y  = blk >> 3;
    int t  = threadIdx.x;
    int w  = t >> 6;
    int l  = t & 63;
    int quad = l >> 4;
    int l15  = l & 15;
    int mt   = w & 1;
    int o16  = w >> 1;
    int x0   = xh * 32;
    const __bf16* inb = t_bf + (size_t)bb * HWW * CC;

    int cu = t & 31;
    int cbase = cu * 8;
    float mu = stats[bb * 64 + cu * 2]     * (1.f / GN_CNT);
    float ms = stats[bb * 64 + cu * 2 + 1] * (1.f / GN_CNT);
    float rs = rsqrtf(ms - mu * mu + 1e-5f);
    float sc[8], sh[8];
    #pragma unroll
    for (int j = 0; j < 8; ++j) {
        float ga = gamma[cbase + j];
        sc[j] = rs * ga;
        sh[j] = beta[cbase + j] - mu * rs * ga;
    }

    f32x4 acc = (f32x4){0.f, 0.f, 0.f, 0.f};

    for (int ky = 0; ky < 3; ++ky) {
        int yy = y + ky - 1;
        bool yok = (yy >= 0 && yy < HH);
        __syncthreads();
        for (int u = t; u < 34 * 32; u += 256) {
            int xl = u >> 5;
            int gx = x0 - 1 + xl;
            uint4 val = make_uint4(0u, 0u, 0u, 0u);
            if (yok && gx >= 0 && gx < WW) {
                uint4 q = *(const uint4*)(inb + ((size_t)(yy * WW + gx)) * CC + cu * 8);
                __bf16 o8[8];
                unsigned qq[4] = {q.x, q.y, q.z, q.w};
                #pragma unroll
                for (int h = 0; h < 4; ++h) {
                    float lo = fmaxf(bflo(qq[h]) * sc[h*2]   + sh[h*2],   0.f);
                    float hi = fmaxf(bfhi(qq[h]) * sc[h*2+1] + sh[h*2+1], 0.f);
                    o8[h*2]   = (__bf16)lo;
                    o8[h*2+1] = (__bf16)hi;
                }
                val = *(const uint4*)o8;
            }
            *(uint4*)&Vt[VT256_RD(xl, cu)] = val;
        }
        __syncthreads();
        #pragma unroll
        for (int kx = 0; kx < 3; ++kx) {
            int k = ky * 3 + kx;
            const bf16x8* wbase = (const bf16x8*)(wf18 + (size_t)k * 8192);
            for (int c0 = 0; c0 < 8; ++c0) {
                int row = mt * 16 + l15 + kx;
                bf16x8 a = *(const bf16x8*)&Vt[VT256_RD(row, c0 * 4 + quad)];
                bf16x8 bfr = wbase[(c0 * 2 + o16) * 64 + l];
                acc = __builtin_amdgcn_mfma_f32_16x16x32_bf16(a, bfr, acc, 0, 0, 0);
            }
        }
    }
    {
        int o = o16 * 16 + l15;
        if (o < 18) {
            float bi = bias[o];
            float4 st;
            st.x = acc[0] + bi;
            st.y = acc[1] + bi;
            st.z = acc[2] + bi;
            st.w = acc[3] + bi;
            *(float4*)(pts + (((size_t)bb*18 + o)*HH + y)*WW + x0 + mt*16 + quad*4) = st;
        }
    }
}

// ---------------------------------------------------------------------------
// Deformable conv via bf16 MFMA, 1024-thread blocks (16 waves), y-PAIR per
// block: 128 px x 256 o -> weight L2 traffic per px halves. R8 pipeline shape.
// grid 256: blk&7=b*2+which (XCD locality), y0 = (blk>>3)*2.
__global__ __launch_bounds__(1024, 1) void deform_mfma(
    const __bf16* __restrict__ cls_cl, const __bf16* __restrict__ reg_cl,
    const __bf16* __restrict__ wfc, const __bf16* __restrict__ wfr,
    const float* __restrict__ pts,
    __bf16* __restrict__ out_cls, __bf16* __restrict__ out_reg,
    float* __restrict__ stats)
{
    __shared__ float pairW4[1152 * 4];    // 18 KB
    __shared__ int   pairO4[1152 * 4];    // 18 KB
    __shared__ __bf16 Vt[2][128 * 128];   // 2 x 32 KB (c-half tiles, 128 px)
    __shared__ float groupStats[64];

    int blk = blockIdx.x;
    int g8  = blk & 7;
    int which = g8 & 1;
    int bb  = g8 >> 1;
    int y0  = (blk >> 3) * 2;
    const __bf16* featb = (which ? reg_cl : cls_cl) + (size_t)bb * HWW * CC;
    const __bf16* wf    = which ? wfr : wfc;
    __bf16* outp  = which ? out_reg : out_cls;
    float* statsP = stats + 256 + which * 256 + bb * 64;

    int t = threadIdx.x;        // 0..1023
    int w = t >> 6;             // 0..15
    int l = t & 63;
    int quad = l >> 4;
    int l15  = l & 15;
    int cq4  = t & 15;          // 16B chunk within 256B half-row
    int sg   = t >> 4;          // site sub-index 0..63
    int ow   = w & 7;           // o-range of wave
    int rh   = w >> 3;          // row-half of wave

    if (t < 64) groupStats[t] = 0.f;
    // phase 0: bilinear weights + corner element offsets per (k, site);
    // site = r*64 + x, r in {0,1}, sampling row y0+r.
    for (int j = t; j < 1152; j += 1024) {
        int k = j >> 7;
        int site = j & 127;
        int r = site >> 6;
        int x = site & 63;
        int y = y0 + r;
        float py  = pts[(((size_t)bb*18 + 2*k)*HH + y)*WW + x] + (float)y;
        float pxf = pts[(((size_t)bb*18 + 2*k + 1)*HH + y)*WW + x] + (float)x;
        float y0f = floorf(py), x0f = floorf(pxf);
        float wy = py - y0f, wx = pxf - x0f;
        int iy0 = (int)y0f, ix0 = (int)x0f;
        int iy1 = iy0 + 1,  ix1 = ix0 + 1;
        bool vy0 = (iy0 >= 0 && iy0 < HH), vy1 = (iy1 >= 0 && iy1 < HH);
        bool vx0 = (ix0 >= 0 && ix0 < WW), vx1 = (ix1 >= 0 && ix1 < WW);
        int cy0 = min(max(iy0, 0), HH-1), cy1 = min(max(iy1, 0), HH-1);
        int cx0 = min(max(ix0, 0), WW-1), cx1 = min(max(ix1, 0), WW-1);
        pairW4[j*4+0] = (1.f-wy)*(1.f-wx) * ((vy0 && vx0) ? 1.f : 0.f);
        pairW4[j*4+1] = (1.f-wy)*wx       * ((vy0 && vx1) ? 1.f : 0.f);
        pairW4[j*4+2] = wy*(1.f-wx)       * ((vy1 && vx0) ? 1.f : 0.f);
        pairW4[j*4+3] = wy*wx             * ((vy1 && vx1) ? 1.f : 0.f);
        pairO4[j*4+0] = (cy0*WW + cx0)*CC;
        pairO4[j*4+1] = (cy0*WW + cx1)*CC;
        pairO4[j*4+2] = (cy1*WW + cx0)*CC;
        pairO4[j*4+3] = (cy1*WW + cx1)*CC;
    }

    f32x4 acc[2][4];   // [ot][pt]
    #pragma unroll
    for (int i = 0; i < 2; ++i)
        #pragma unroll
        for (int j = 0; j < 4; ++j)
            acc[i][j] = (f32x4){0.f, 0.f, 0.f, 0.f};

    uint4 L[2][4];

    // issue gather loads for stage s (2 site-chunks x 4 corners, 16B each)
    auto gathers = [&](int s) {
        int k = s >> 1, ch = s & 1;
        const __bf16* fb = featb + ch * 128 + cq4 * 8;
        #pragma unroll
        for (int it = 0; it < 2; ++it) {
            int j = k * 128 + it * 64 + sg;
            int4 ov = *(const int4*)&pairO4[j * 4];
            L[it][0] = *(const uint4*)(fb + ov.x);
            L[it][1] = *(const uint4*)(fb + ov.y);
            L[it][2] = *(const uint4*)(fb + ov.z);
            L[it][3] = *(const uint4*)(fb + ov.w);
        }
    };
    // packed bilinear combine + b128 write to buf[s&1]
    auto combine = [&](int s) {
        __bf16* buf = &Vt[s & 1][0];
        int k = s >> 1;
        #pragma unroll
        for (int it = 0; it < 2; ++it) {
            int site = it * 64 + sg;
            float4 wv = *(const float4*)&pairW4[(k * 128 + site) * 4];
            __bf16 o8[8];
            unsigned q0[4] = {L[it][0].x, L[it][0].y, L[it][0].z, L[it][0].w};
            unsigned q1[4] = {L[it][1].x, L[it][1].y, L[it][1].z, L[it][1].w};
            unsigned q2[4] = {L[it][2].x, L[it][2].y, L[it][2].z, L[it][2].w};
            unsigned q3[4] = {L[it][3].x, L[it][3].y, L[it][3].z, L[it][3].w};
            #pragma unroll
            for (int h = 0; h < 4; ++h) {
                f32x2 r = wv.x * up2(q0[h]);
                r += wv.y * up2(q1[h]);
                r += wv.z * up2(q2[h]);
                r += wv.w * up2(q3[h]);
                o8[h*2]   = (__bf16)r.x;
                o8[h*2+1] = (__bf16)r.y;
            }
            *(uint4*)&buf[VT128_RD(site, cq4)] = *(const uint4*)o8;
        }
    };
    // MFMAs of stage s from buf[s&1]; wave covers row-half rh, o-range ow*32
    auto stage_mfma = [&](int s) {
        int ch = s & 1;
        const __bf16* buf = &Vt[s & 1][0];
        const bf16x8* wbase = (const bf16x8*)(wf + (size_t)(s >> 1) * 65536);
        #pragma unroll
        for (int u = 0; u < 4; ++u) {
            bf16x8 a[4], bfr[2];
            #pragma unroll
            for (int pt = 0; pt < 4; ++pt) {
                int row = rh * 64 + pt * 16 + l15;
                a[pt] = *(const bf16x8*)&buf[VT128_RD(row, u * 4 + quad)];
            }
            #pragma unroll
            for (int ot = 0; ot < 2; ++ot)
                bfr[ot] = wbase[(((ch * 4 + u) * 16) + (ow * 2 + ot)) * 64 + l];
            #pragma unroll
            for (int ot = 0; ot < 2; ++ot)
                #pragma unroll
                for (int pt = 0; pt < 4; ++pt)
                    acc[ot][pt] = __builtin_amdgcn_mfma_f32_16x16x32_bf16(
                        bfr[ot], a[pt], acc[ot][pt], 0, 0, 0);
        }
    };

    __syncthreads();
    gathers(0);
    combine(0);
    #pragma unroll 1
    for (int s = 1; s < 18; ++s) {
        __syncthreads();
        gathers(s);
        stage_mfma(s - 1);
        combine(s);
    }
    __syncthreads();
    stage_mfma(17);

    // epilogue: D[m=o][n=px]; o = ow*32 + ot*16 + quad*4 + r; px = pt*16+l15,
    // output row y0+rh.
    #pragma unroll
    for (int ot = 0; ot < 2; ++ot) {
        float s1 = 0.f, s2 = 0.f;
        #pragma unroll
        for (int r = 0; r < 4; ++r) {
            int o = ow * 32 + ot * 16 + quad * 4 + r;
            __bf16* orow = outp + ((size_t)(bb*CC + o))*HWW + (y0 + rh)*WW + l15;
            #pragma unroll
            for (int pt = 0; pt < 4; ++pt) {
                float v = acc[ot][pt][r];
                orow[pt * 16] = (__bf16)v;
                s1 += v; s2 += v * v;
            }
        }
        s1 += __shfl_xor(s1, 1, 64); s1 += __shfl_xor(s1, 2, 64);
        s1 += __shfl_xor(s1, 4, 64); s1 += __shfl_xor(s1, 8, 64);
        s1 += __shfl_xor(s1, 16, 64);
        s2 += __shfl_xor(s2, 1, 64); s2 += __shfl_xor(s2, 2, 64);
        s2 += __shfl_xor(s2, 4, 64); s2 += __shfl_xor(s2, 8, 64);
        s2 += __shfl_xor(s2, 16, 64);
        if ((l & 31) == 0) {
            int g = ow * 4 + ot * 2 + (l >> 5);
            atomicAdd(&groupStats[g * 2],     s1);
            atomicAdd(&groupStats[g * 2 + 1], s2);
        }
    }
    __syncthreads();
    if (t < 64) atomicAdd(&statsP[t], groupStats[t]);
}

// ---------------------------------------------------------------------------
// GN + ReLU on bf16 NCHW deform outputs -> fp32 final outputs. 8 elems/thread.
__global__ void gn_relu_nchw(const __bf16* __restrict__ in_cls, const __bf16* __restrict__ in_reg,
                             float* __restrict__ out_cls, float* __restrict__ out_reg,
                             const float* __restrict__ stats_base,
                             const float* __restrict__ gcls, const float* __restrict__ bcls,
                             const float* __restrict__ greg, const float* __restrict__ breg) {
    int which = blockIdx.y;
    const __bf16* in = which ? in_reg  : in_cls;
    float* out       = which ? out_reg : out_cls;
    const float* st  = stats_base + (which ? 512 : 256);
    const float* gg  = which ? greg : gcls;
    const float* be  = which ? breg : bcls;
    size_t e = ((size_t)blockIdx.x * 256 + threadIdx.x) * 8;
    int c = (int)((e >> 12) & 255);
    int b = (int)(e >> 20);
    int g = c >> 3;
    float mu = st[(b*32 + g)*2] * (1.f / GN_CNT);
    float ms = st[(b*32 + g)*2 + 1] * (1.f / GN_CNT);
    float rs = rsqrtf(ms - mu*mu + 1e-5f);
    float ga = gg[c], bb = be[c];
    uint4 q = *(const uint4*)(in + e);
    float v[8] = {bflo(q.x), bfhi(q.x), bflo(q.y), bfhi(q.y),
                  bflo(q.z), bfhi(q.z), bflo(q.w), bfhi(q.w)};
    float4 r0, r1;
    r0.x = fmaxf((v[0] - mu)*rs*ga + bb, 0.f);
    r0.y = fmaxf((v[1] - mu)*rs*ga + bb, 0.f);
    r0.z = fmaxf((v[2] - mu)*rs*ga + bb, 0.f);
    r0.w = fmaxf((v[3] - mu)*rs*ga + bb, 0.f);
    r1.x = fmaxf((v[4] - mu)*rs*ga + bb, 0.f);
    r1.y = fmaxf((v[5] - mu)*rs*ga + bb, 0.f);
    r1.z = fmaxf((v[6] - mu)*rs*ga + bb, 0.f);
    r1.w = fmaxf((v[7] - mu)*rs*ga + bb, 0.f);
    *(float4*)(out + e)     = r0;
    *(float4*)(out + e + 4) = r1;
}

// ---------------------------------------------------------------------------
extern "C" void kernel_launch(void* const* d_in, const int* in_sizes, int n_in,
                              void* d_out, int out_size, void* d_ws, size_t ws_size,
                              hipStream_t stream) {
    (void)in_sizes; (void)n_in; (void)out_size; (void)ws_size;
    const float* cls_feat = (const float*)d_in[0];
    const float* reg_feat = (const float*)d_in[1];
    const float* offc_w   = (const float*)d_in[2];
    const float* offc_b   = (const float*)d_in[3];
    const float* offc_g   = (const float*)d_in[4];
    const float* offc_bt  = (const float*)d_in[5];
    const float* offo_w   = (const float*)d_in[6];
    const float* offo_b   = (const float*)d_in[7];
    const float* clsdc_w  = (const float*)d_in[8];
    const float* cls_g    = (const float*)d_in[9];
    const float* cls_bt   = (const float*)d_in[10];
    const float* regdc_w  = (const float*)d_in[11];
    const float* reg_g    = (const float*)d_in[12];
    const float* reg_bt   = (const float*)d_in[13];
    float* out = (float*)d_out;

    char* ws = (char*)d_ws;
    __bf16* reg_cl = (__bf16*)ws;                        // 8 MB
    __bf16* cls_cl = (__bf16*)(ws + 8388608);            // 8 MB
    __bf16* t_bf   = (__bf16*)(ws + 16777216);           // 8 MB
    __bf16* dc_cls = (__bf16*)(ws + 25165824);           // 8 MB
    __bf16* dc_reg = (__bf16*)(ws + 33554432);           // 8 MB
    __bf16* wt1f   = (__bf16*)(ws + 41943040);           // 1.18 MB
    __bf16* wtcf   = (__bf16*)(ws + 41943040 + 1179648);
    __bf16* wtrf   = (__bf16*)(ws + 41943040 + 2359296);
    __bf16* wf18   = (__bf16*)(ws + 41943040 + 3538944); // 147 KB
    float*  stats  = (float*)(ws + 41943040 + 3686400);  // 768 floats

    float* pts     = out;                 // [4,18,64,64]
    float* out_cls = out + 294912;
    float* out_reg = out + 294912 + FEL;

    hipLaunchKernelGGL(prep_and_transpose, dim3(9248), dim3(256), 0, stream,
                       cls_feat, reg_feat, cls_cl, reg_cl,
                       offc_w, clsdc_w, regdc_w, offo_w,
                       wt1f, wtcf, wtrf, wf18, stats);
    hipLaunchKernelGGL(conv1_mfma, dim3(256), dim3(512), 0, stream,
                       reg_cl, wt1f, offc_b, t_bf, stats);
    hipLaunchKernelGGL(conv18_mfma, dim3(512), dim3(256), 0, stream,
                       t_bf, wf18, offo_b, stats, offc_g, offc_bt, pts);
    hipLaunchKernelGGL(deform_mfma, dim3(256), dim3(1024), 0, stream,
                       cls_cl, reg_cl, wtcf, wtrf, pts, dc_cls, dc_reg, stats);
    hipLaunchKernelGGL(gn_relu_nchw, dim3(2048, 2), dim3(256), 0, stream,
                       dc_cls, dc_reg, out_cls, out_reg,
                       stats, cls_g, cls_bt, reg_g, reg_bt);
}

// Round 10
// 233.252 us; speedup vs baseline: 1.0283x; 1.0283x over previous
//
#include <hip/hip_runtime.h>
#include <math.h>

#define BB 4
#define CC 256
#define HH 64
#define WW 64
#define KP 9
#define GG 32
#define HWW (HH*WW)                 // 4096
#define FEL ((size_t)BB*CC*HH*WW)   // 4194304
#define GN_CNT 32768.0f             // (CC/GG)*H*W

typedef __bf16 bf16x8 __attribute__((ext_vector_type(8)));
typedef float  f32x4  __attribute__((ext_vector_type(4)));
typedef float  f32x2  __attribute__((ext_vector_type(2)));

__device__ __forceinline__ float bflo(unsigned u) {
    union { unsigned u; float f; } x; x.u = u << 16; return x.f;
}
__device__ __forceinline__ float bfhi(unsigned u) {
    union { unsigned u; float f; } x; x.u = u & 0xffff0000u; return x.f;
}
__device__ __forceinline__ f32x2 up2(unsigned u) {
    return (f32x2){bflo(u), bfhi(u)};
}

// XOR-swizzled LDS addressing (swizzle by row&15: 16-way spread, conflict-free
// for MFMA A-reads where 16 lanes differ in row low bits).
// 256-element (512 B) rows; P = 16B chunk 0..31:
#define VT256_RD(row, P)  (((row) << 8) + ((((P) ^ ((row) & 15))) << 3))
// 128-element (256 B) rows; P = 16B chunk 0..15:
#define VT128_RD(row, P)  (((row) << 7) + ((((P) ^ ((row) & 15))) << 3))

// ---------------------------------------------------------------------------
// Fused: NCHW fp32 -> NHWC bf16 transpose (blocks 0..2047) + all weight-frag
// prep + stats zeroing (blocks 2048..9247).
__global__ void prep_and_transpose(
    const float* __restrict__ cls, const float* __restrict__ reg,
    __bf16* __restrict__ out_cls, __bf16* __restrict__ out_reg,
    const float* __restrict__ w1, const float* __restrict__ wc,
    const float* __restrict__ wr, const float* __restrict__ w18,
    __bf16* __restrict__ f1, __bf16* __restrict__ fc,
    __bf16* __restrict__ fr, __bf16* __restrict__ f18,
    float* __restrict__ stats)
{
    int blk = blockIdx.x;
    if (blk < 2048) {
        __shared__ float tile[64][65];
        int c0 = (blk & 3) * 64;
        int y  = (blk >> 2) & 63;
        int z  = blk >> 8;
        int b  = z & 3;
        const float* in = (z >> 2) ? reg : cls;
        __bf16* out     = (z >> 2) ? out_reg : out_cls;
        int lx = threadIdx.x & 63;
        int q  = threadIdx.x >> 6;
        for (int j = 0; j < 16; ++j) {
            int ci = q * 16 + j;
            tile[ci][lx] = in[(((size_t)b*CC + c0 + ci)*HH + y)*WW + lx];
        }
        __syncthreads();
        for (int j = 0; j < 16; ++j) {
            int xi = q * 16 + j;
            out[(((size_t)b*HH + y)*WW + xi)*CC + c0 + lx] = (__bf16)tile[lx][xi];
        }
        return;
    }
    int gid = (blk - 2048) * 256 + threadIdx.x;
    if (gid < 768) stats[gid] = 0.f;
    const int NW = 589824;
    if (gid < 3 * NW) {
        int which = gid / NW;
        int idx = gid - which * NW;
        int j   = idx & 7;
        int l   = (idx >> 3) & 63;
        int o16 = (idx >> 9) & 15;
        int c0  = (idx >> 13) & 7;
        int k   = idx >> 16;
        int o = o16 * 16 + (l & 15);
        int c = c0 * 32 + (l >> 4) * 8 + j;
        const float* src = (which == 0) ? w1 : ((which == 1) ? wc : wr);
        __bf16* dst = (which == 0) ? f1 : ((which == 1) ? fc : fr);
        dst[idx] = (__bf16)src[(size_t)(o * 256 + c) * 9 + k];
    } else {
        int idx = gid - 3 * NW;   // < 73728
        int j   = idx & 7;
        int l   = (idx >> 3) & 63;
        int o16 = (idx >> 9) & 1;
        int c0  = (idx >> 10) & 7;
        int k   = idx >> 13;
        int o = o16 * 16 + (l & 15);
        int c = c0 * 32 + (l >> 4) * 8 + j;
        float v = (o < 18) ? w18[(size_t)(o * 256 + c) * 9 + k] : 0.f;
        f18[idx] = (__bf16)v;
    }
}

// ---------------------------------------------------------------------------
// conv3x3 C256->C256 via bf16 MFMA. Wave tile 32px x 32o (pt=2, ot=2):
// 2 ds_read + 2 wloads -> 4 MFMA (0.5 ds_read/MFMA). Block = 64px x 64o,
// 4 waves: w&1 = px-half, w>>1 = o-32-half. grid 1024: blk&3=b,
// (blk>>2)&3=oq, y=blk>>4. 4 blocks/CU (same occupancy as R8).
__global__ __launch_bounds__(256, 4) void conv1_mfma(
    const __bf16* __restrict__ in_cl,   // [B,H,W,256] bf16
    const __bf16* __restrict__ wf,      // frag [9][8][16][64][8]
    const float* __restrict__ bias,
    __bf16* __restrict__ t_out,         // [B,H,W,256] bf16 (pre-GN)
    float* __restrict__ stats)
{
    __shared__ __bf16 Vt[66 * 256];
    __shared__ float groupStats[64];
    int blk = blockIdx.x;
    int bb = blk & 3;
    int oq = (blk >> 2) & 3;
    int y  = blk >> 4;
    int t  = threadIdx.x;
    int w  = t >> 6;
    int l  = t & 63;
    int quad = l >> 4;
    int l15  = l & 15;
    int ph  = w & 1;     // px-half (32 px)
    int oh2 = w >> 1;    // o-32-half within the 64-o quarter
    if (t < 64) groupStats[t] = 0.f;

    const __bf16* inb = in_cl + (size_t)bb * HWW * CC;
    f32x4 acc[2][2];   // [pt][ot]
    #pragma unroll
    for (int i = 0; i < 2; ++i)
        #pragma unroll
        for (int j = 0; j < 2; ++j)
            acc[i][j] = (f32x4){0.f, 0.f, 0.f, 0.f};

    for (int ky = 0; ky < 3; ++ky) {
        int yy = y + ky - 1;
        bool yok = (yy >= 0 && yy < HH);
        __syncthreads();
        for (int u = t; u < 66 * 32; u += 256) {
            int xl = u >> 5, cu = u & 31;
            int gx = xl - 1;
            uint4 val = make_uint4(0u, 0u, 0u, 0u);
            if (yok && gx >= 0 && gx < WW)
                val = *(const uint4*)(inb + ((size_t)(yy * WW + gx)) * CC + cu * 8);
            *(uint4*)&Vt[VT256_RD(xl, cu)] = val;
        }
        __syncthreads();
        #pragma unroll
        for (int kx = 0; kx < 3; ++kx) {
            int k = ky * 3 + kx;
            const bf16x8* wbase = (const bf16x8*)(wf + (size_t)k * 65536);
            for (int c0 = 0; c0 < 8; ++c0) {
                bf16x8 a[2], bfr[2];
                #pragma unroll
                for (int pt = 0; pt < 2; ++pt) {
                    int row = ph * 32 + pt * 16 + l15 + kx;
                    a[pt] = *(const bf16x8*)&Vt[VT256_RD(row, c0 * 4 + quad)];
                }
                #pragma unroll
                for (int ot = 0; ot < 2; ++ot)
                    bfr[ot] = wbase[(c0 * 16 + (oq * 4 + oh2 * 2 + ot)) * 64 + l];
                #pragma unroll
                for (int pt = 0; pt < 2; ++pt)
                    #pragma unroll
                    for (int ot = 0; ot < 2; ++ot)
                        acc[pt][ot] = __builtin_amdgcn_mfma_f32_16x16x32_bf16(
                            a[pt], bfr[ot], acc[pt][ot], 0, 0, 0);
            }
        }
    }
    // D[m=px][n=o]; px = ph*32 + pt*16 + quad*4 + r; o = oq*64 + oh2*32 + ot*16 + l15
    #pragma unroll
    for (int ot = 0; ot < 2; ++ot) {
        int o = oq * 64 + oh2 * 32 + ot * 16 + l15;
        float bi = bias[o];
        float s1 = 0.f, s2 = 0.f;
        #pragma unroll
        for (int pt = 0; pt < 2; ++pt)
            #pragma unroll
            for (int r = 0; r < 4; ++r) {
                float v = acc[pt][ot][r] + bi;
                int px = ph * 32 + pt * 16 + quad * 4 + r;
                t_out[(((size_t)bb * HH + y) * WW + px) * CC + o] = (__bf16)v;
                s1 += v; s2 += v * v;
            }
        s1 += __shfl_xor(s1, 16, 64); s1 += __shfl_xor(s1, 32, 64);
        s2 += __shfl_xor(s2, 16, 64); s2 += __shfl_xor(s2, 32, 64);
        if (quad == 0) {
            atomicAdd(&groupStats[(o >> 3) * 2],     s1);
            atomicAdd(&groupStats[(o >> 3) * 2 + 1], s2);
        }
    }
    __syncthreads();
    if (t < 64) atomicAdd(&stats[bb * 64 + t], groupStats[t]);
}

// ---------------------------------------------------------------------------
// Offset head conv3x3 C256->18 via bf16 MFMA, GN+ReLU fused into 16B staging.
// Half-row split: grid 512, blk&3=b, (blk>>2)&1=xh, y=blk>>3.
__global__ __launch_bounds__(256, 4) void conv18_mfma(
    const __bf16* __restrict__ t_bf,    // [B,H,W,256] bf16 raw (pre-GN)
    const __bf16* __restrict__ wf18,    // frag [9][8][2][64][8]
    const float* __restrict__ bias,     // [18]
    const float* __restrict__ stats,    // conv1 GN stats, + b*64
    const float* __restrict__ gamma, const float* __restrict__ beta,
    float* __restrict__ pts)            // [B,18,H,W]
{
    __shared__ __bf16 Vt[34 * 256];
    int blk = blockIdx.x;
    int bb = blk & 3;
    int xh = (blk >> 2) & 1;
    int y  = blk >> 3;
    int t  = threadIdx.x;
    int w  = t >> 6;
    int l  = t & 63;
    int quad = l >> 4;
    int l15  = l & 15;
    int mt   = w & 1;
    int o16  = w >> 1;
    int x0   = xh * 32;
    const __bf16* inb = t_bf + (size_t)bb * HWW * CC;

    int cu = t & 31;
    int cbase = cu * 8;
    float mu = stats[bb * 64 + cu * 2]     * (1.f / GN_CNT);
    float ms = stats[bb * 64 + cu * 2 + 1] * (1.f / GN_CNT);
    float rs = rsqrtf(ms - mu * mu + 1e-5f);
    float sc[8], sh[8];
    #pragma unroll
    for (int j = 0; j < 8; ++j) {
        float ga = gamma[cbase + j];
        sc[j] = rs * ga;
        sh[j] = beta[cbase + j] - mu * rs * ga;
    }

    f32x4 acc = (f32x4){0.f, 0.f, 0.f, 0.f};

    for (int ky = 0; ky < 3; ++ky) {
        int yy = y + ky - 1;
        bool yok = (yy >= 0 && yy < HH);
        __syncthreads();
        for (int u = t; u < 34 * 32; u += 256) {
            int xl = u >> 5;
            int gx = x0 - 1 + xl;
            uint4 val = make_uint4(0u, 0u, 0u, 0u);
            if (yok && gx >= 0 && gx < WW) {
                uint4 q = *(const uint4*)(inb + ((size_t)(yy * WW + gx)) * CC + cu * 8);
                __bf16 o8[8];
                unsigned qq[4] = {q.x, q.y, q.z, q.w};
                #pragma unroll
                for (int h = 0; h < 4; ++h) {
                    float lo = fmaxf(bflo(qq[h]) * sc[h*2]   + sh[h*2],   0.f);
                    float hi = fmaxf(bfhi(qq[h]) * sc[h*2+1] + sh[h*2+1], 0.f);
                    o8[h*2]   = (__bf16)lo;
                    o8[h*2+1] = (__bf16)hi;
                }
                val = *(const uint4*)o8;
            }
            *(uint4*)&Vt[VT256_RD(xl, cu)] = val;
        }
        __syncthreads();
        #pragma unroll
        for (int kx = 0; kx < 3; ++kx) {
            int k = ky * 3 + kx;
            const bf16x8* wbase = (const bf16x8*)(wf18 + (size_t)k * 8192);
            for (int c0 = 0; c0 < 8; ++c0) {
                int row = mt * 16 + l15 + kx;
                bf16x8 a = *(const bf16x8*)&Vt[VT256_RD(row, c0 * 4 + quad)];
                bf16x8 bfr = wbase[(c0 * 2 + o16) * 64 + l];
                acc = __builtin_amdgcn_mfma_f32_16x16x32_bf16(a, bfr, acc, 0, 0, 0);
            }
        }
    }
    {
        int o = o16 * 16 + l15;
        if (o < 18) {
            float bi = bias[o];
            float4 st;
            st.x = acc[0] + bi;
            st.y = acc[1] + bi;
            st.z = acc[2] + bi;
            st.w = acc[3] + bi;
            *(float4*)(pts + (((size_t)bb*18 + o)*HH + y)*WW + x0 + mt*16 + quad*4) = st;
        }
    }
}

// ---------------------------------------------------------------------------
// Deformable conv via bf16 MFMA, 512-thread blocks (8 waves, 32 o each),
// R8 pipeline shape (compiler-scheduled) + 16B gathers + packed-f32 combine.
// grid 512: blk&7=b*2+which (XCD locality), y=blk>>3.
__global__ __launch_bounds__(512, 4) void deform_mfma(
    const __bf16* __restrict__ cls_cl, const __bf16* __restrict__ reg_cl,
    const __bf16* __restrict__ wfc, const __bf16* __restrict__ wfr,
    const float* __restrict__ pts,
    __bf16* __restrict__ out_cls, __bf16* __restrict__ out_reg,
    float* __restrict__ stats)
{
    __shared__ float pairW4[576 * 4];    // 9216 B
    __shared__ int   pairO4[576 * 4];    // 9216 B
    __shared__ __bf16 Vt[2][64 * 128];   // 2 x 16 KB (c-half tiles)
    __shared__ float groupStats[64];

    int blk = blockIdx.x;
    int g8  = blk & 7;
    int which = g8 & 1;
    int bb  = g8 >> 1;
    int y   = blk >> 3;
    const __bf16* featb = (which ? reg_cl : cls_cl) + (size_t)bb * HWW * CC;
    const __bf16* wf    = which ? wfr : wfc;
    __bf16* outp  = which ? out_reg : out_cls;
    float* statsP = stats + 256 + which * 256 + bb * 64;

    int t = threadIdx.x;        // 0..511
    int w = t >> 6;             // 0..7
    int l = t & 63;
    int quad = l >> 4;
    int l15  = l & 15;
    int cq4  = t & 15;          // 16B chunk within 256B half-row
    int pxg  = t >> 4;          // px sub-index 0..31

    if (t < 64) groupStats[t] = 0.f;
    // phase 0: bilinear weights + corner element offsets per (k, px)
    for (int j = t; j < 576; j += 512) {
        int k = j >> 6;
        int x = j & 63;
        float py  = pts[(((size_t)bb*18 + 2*k)*HH + y)*WW + x] + (float)y;
        float pxf = pts[(((size_t)bb*18 + 2*k + 1)*HH + y)*WW + x] + (float)x;
        float y0f = floorf(py), x0f = floorf(pxf);
        float wy = py - y0f, wx = pxf - x0f;
        int iy0 = (int)y0f, ix0 = (int)x0f;
        int iy1 = iy0 + 1,  ix1 = ix0 + 1;
        bool vy0 = (iy0 >= 0 && iy0 < HH), vy1 = (iy1 >= 0 && iy1 < HH);
        bool vx0 = (ix0 >= 0 && ix0 < WW), vx1 = (ix1 >= 0 && ix1 < WW);
        int cy0 = min(max(iy0, 0), HH-1), cy1 = min(max(iy1, 0), HH-1);
        int cx0 = min(max(ix0, 0), WW-1), cx1 = min(max(ix1, 0), WW-1);
        pairW4[j*4+0] = (1.f-wy)*(1.f-wx) * ((vy0 && vx0) ? 1.f : 0.f);
        pairW4[j*4+1] = (1.f-wy)*wx       * ((vy0 && vx1) ? 1.f : 0.f);
        pairW4[j*4+2] = wy*(1.f-wx)       * ((vy1 && vx0) ? 1.f : 0.f);
        pairW4[j*4+3] = wy*wx             * ((vy1 && vx1) ? 1.f : 0.f);
        pairO4[j*4+0] = (cy0*WW + cx0)*CC;
        pairO4[j*4+1] = (cy0*WW + cx1)*CC;
        pairO4[j*4+2] = (cy1*WW + cx0)*CC;
        pairO4[j*4+3] = (cy1*WW + cx1)*CC;
    }

    f32x4 acc[2][4];   // [ot][pt]
    #pragma unroll
    for (int i = 0; i < 2; ++i)
        #pragma unroll
        for (int j = 0; j < 4; ++j)
            acc[i][j] = (f32x4){0.f, 0.f, 0.f, 0.f};

    uint4 L[2][4];

    // issue gather loads for stage s (2 px-chunks x 4 corners, 16B each)
    auto gathers = [&](int s) {
        int k = s >> 1, ch = s & 1;
        const __bf16* fb = featb + ch * 128 + cq4 * 8;
        #pragma unroll
        for (int it = 0; it < 2; ++it) {
            int j = k * 64 + it * 32 + pxg;
            int4 ov = *(const int4*)&pairO4[j * 4];
            L[it][0] = *(const uint4*)(fb + ov.x);
            L[it][1] = *(const uint4*)(fb + ov.y);
            L[it][2] = *(const uint4*)(fb + ov.z);
            L[it][3] = *(const uint4*)(fb + ov.w);
        }
    };
    // packed bilinear combine + b128 write to buf[s&1]
    auto combine = [&](int s) {
        __bf16* buf = &Vt[s & 1][0];
        int k = s >> 1;
        #pragma unroll
        for (int it = 0; it < 2; ++it) {
            int pxi = it * 32 + pxg;
            float4 wv = *(const float4*)&pairW4[(k * 64 + pxi) * 4];
            __bf16 o8[8];
            unsigned q0[4] = {L[it][0].x, L[it][0].y, L[it][0].z, L[it][0].w};
            unsigned q1[4] = {L[it][1].x, L[it][1].y, L[it][1].z, L[it][1].w};
            unsigned q2[4] = {L[it][2].x, L[it][2].y, L[it][2].z, L[it][2].w};
            unsigned q3[4] = {L[it][3].x, L[it][3].y, L[it][3].z, L[it][3].w};
            #pragma unroll
            for (int h = 0; h < 4; ++h) {
                f32x2 r = wv.x * up2(q0[h]);
                r += wv.y * up2(q1[h]);
                r += wv.z * up2(q2[h]);
                r += wv.w * up2(q3[h]);
                o8[h*2]   = (__bf16)r.x;
                o8[h*2+1] = (__bf16)r.y;
            }
            *(uint4*)&buf[VT128_RD(pxi, cq4)] = *(const uint4*)o8;
        }
    };
    // MFMAs of stage s from buf[s&1], weights streamed from L2
    auto stage_mfma = [&](int s) {
        int ch = s & 1;
        const __bf16* buf = &Vt[s & 1][0];
        const bf16x8* wbase = (const bf16x8*)(wf + (size_t)(s >> 1) * 65536);
        #pragma unroll
        for (int u = 0; u < 4; ++u) {
            bf16x8 a[4], bfr[2];
            #pragma unroll
            for (int pt = 0; pt < 4; ++pt)
                a[pt] = *(const bf16x8*)&buf[VT128_RD(pt * 16 + l15, u * 4 + quad)];
            #pragma unroll
            for (int ot = 0; ot < 2; ++ot)
                bfr[ot] = wbase[(((ch * 4 + u) * 16) + (w * 2 + ot)) * 64 + l];
            #pragma unroll
            for (int ot = 0; ot < 2; ++ot)
                #pragma unroll
                for (int pt = 0; pt < 4; ++pt)
                    acc[ot][pt] = __builtin_amdgcn_mfma_f32_16x16x32_bf16(
                        bfr[ot], a[pt], acc[ot][pt], 0, 0, 0);
        }
    };

    __syncthreads();
    gathers(0);
    combine(0);
    #pragma unroll 1
    for (int s = 1; s < 18; ++s) {
        __syncthreads();
        gathers(s);
        stage_mfma(s - 1);
        combine(s);
    }
    __syncthreads();
    stage_mfma(17);

    // epilogue: D[m=o][n=px]; o = w*32 + ot*16 + quad*4 + r; px = pt*16 + l15
    #pragma unroll
    for (int ot = 0; ot < 2; ++ot) {
        float s1 = 0.f, s2 = 0.f;
        #pragma unroll
        for (int r = 0; r < 4; ++r) {
            int o = w * 32 + ot * 16 + quad * 4 + r;
            __bf16* orow = outp + ((size_t)(bb*CC + o))*HWW + y*WW + l15;
            #pragma unroll
            for (int pt = 0; pt < 4; ++pt) {
                float v = acc[ot][pt][r];
                orow[pt * 16] = (__bf16)v;
                s1 += v; s2 += v * v;
            }
        }
        s1 += __shfl_xor(s1, 1, 64); s1 += __shfl_xor(s1, 2, 64);
        s1 += __shfl_xor(s1, 4, 64); s1 += __shfl_xor(s1, 8, 64);
        s1 += __shfl_xor(s1, 16, 64);
        s2 += __shfl_xor(s2, 1, 64); s2 += __shfl_xor(s2, 2, 64);
        s2 += __shfl_xor(s2, 4, 64); s2 += __shfl_xor(s2, 8, 64);
        s2 += __shfl_xor(s2, 16, 64);
        if ((l & 31) == 0) {
            int g = w * 4 + ot * 2 + (l >> 5);
            atomicAdd(&groupStats[g * 2],     s1);
            atomicAdd(&groupStats[g * 2 + 1], s2);
        }
    }
    __syncthreads();
    if (t < 64) atomicAdd(&statsP[t], groupStats[t]);
}

// ---------------------------------------------------------------------------
// GN + ReLU on bf16 NCHW deform outputs -> fp32 final outputs. 8 elems/thread.
__global__ void gn_relu_nchw(const __bf16* __restrict__ in_cls, const __bf16* __restrict__ in_reg,
                             float* __restrict__ out_cls, float* __restrict__ out_reg,
                             const float* __restrict__ stats_base,
                             const float* __restrict__ gcls, const float* __restrict__ bcls,
                             const float* __restrict__ greg, const float* __restrict__ breg) {
    int which = blockIdx.y;
    const __bf16* in = which ? in_reg  : in_cls;
    float* out       = which ? out_reg : out_cls;
    const float* st  = stats_base + (which ? 512 : 256);
    const float* gg  = which ? greg : gcls;
    const float* be  = which ? breg : bcls;
    size_t e = ((size_t)blockIdx.x * 256 + threadIdx.x) * 8;
    int c = (int)((e >> 12) & 255);
    int b = (int)(e >> 20);
    int g = c >> 3;
    float mu = st[(b*32 + g)*2] * (1.f / GN_CNT);
    float ms = st[(b*32 + g)*2 + 1] * (1.f / GN_CNT);
    float rs = rsqrtf(ms - mu*mu + 1e-5f);
    float ga = gg[c], bb = be[c];
    uint4 q = *(const uint4*)(in + e);
    float v[8] = {bflo(q.x), bfhi(q.x), bflo(q.y), bfhi(q.y),
                  bflo(q.z), bfhi(q.z), bflo(q.w), bfhi(q.w)};
    float4 r0, r1;
    r0.x = fmaxf((v[0] - mu)*rs*ga + bb, 0.f);
    r0.y = fmaxf((v[1] - mu)*rs*ga + bb, 0.f);
    r0.z = fmaxf((v[2] - mu)*rs*ga + bb, 0.f);
    r0.w = fmaxf((v[3] - mu)*rs*ga + bb, 0.f);
    r1.x = fmaxf((v[4] - mu)*rs*ga + bb, 0.f);
    r1.y = fmaxf((v[5] - mu)*rs*ga + bb, 0.f);
    r1.z = fmaxf((v[6] - mu)*rs*ga + bb, 0.f);
    r1.w = fmaxf((v[7] - mu)*rs*ga + bb, 0.f);
    *(float4*)(out + e)     = r0;
    *(float4*)(out + e + 4) = r1;
}

// ---------------------------------------------------------------------------
extern "C" void kernel_launch(void* const* d_in, const int* in_sizes, int n_in,
                              void* d_out, int out_size, void* d_ws, size_t ws_size,
                              hipStream_t stream) {
    (void)in_sizes; (void)n_in; (void)out_size; (void)ws_size;
    const float* cls_feat = (const float*)d_in[0];
    const float* reg_feat = (const float*)d_in[1];
    const float* offc_w   = (const float*)d_in[2];
    const float* offc_b   = (const float*)d_in[3];
    const float* offc_g   = (const float*)d_in[4];
    const float* offc_bt  = (const float*)d_in[5];
    const float* offo_w   = (const float*)d_in[6];
    const float* offo_b   = (const float*)d_in[7];
    const float* clsdc_w  = (const float*)d_in[8];
    const float* cls_g    = (const float*)d_in[9];
    const float* cls_bt   = (const float*)d_in[10];
    const float* regdc_w  = (const float*)d_in[11];
    const float* reg_g    = (const float*)d_in[12];
    const float* reg_bt   = (const float*)d_in[13];
    float* out = (float*)d_out;

    char* ws = (char*)d_ws;
    __bf16* reg_cl = (__bf16*)ws;                        // 8 MB
    __bf16* cls_cl = (__bf16*)(ws + 8388608);            // 8 MB
    __bf16* t_bf   = (__bf16*)(ws + 16777216);           // 8 MB
    __bf16* dc_cls = (__bf16*)(ws + 25165824);           // 8 MB
    __bf16* dc_reg = (__bf16*)(ws + 33554432);           // 8 MB
    __bf16* wt1f   = (__bf16*)(ws + 41943040);           // 1.18 MB
    __bf16* wtcf   = (__bf16*)(ws + 41943040 + 1179648);
    __bf16* wtrf   = (__bf16*)(ws + 41943040 + 2359296);
    __bf16* wf18   = (__bf16*)(ws + 41943040 + 3538944); // 147 KB
    float*  stats  = (float*)(ws + 41943040 + 3686400);  // 768 floats

    float* pts     = out;                 // [4,18,64,64]
    float* out_cls = out + 294912;
    float* out_reg = out + 294912 + FEL;

    hipLaunchKernelGGL(prep_and_transpose, dim3(9248), dim3(256), 0, stream,
                       cls_feat, reg_feat, cls_cl, reg_cl,
                       offc_w, clsdc_w, regdc_w, offo_w,
                       wt1f, wtcf, wtrf, wf18, stats);
    hipLaunchKernelGGL(conv1_mfma, dim3(1024), dim3(256), 0, stream,
                       reg_cl, wt1f, offc_b, t_bf, stats);
    hipLaunchKernelGGL(conv18_mfma, dim3(512), dim3(256), 0, stream,
                       t_bf, wf18, offo_b, stats, offc_g, offc_bt, pts);
    hipLaunchKernelGGL(deform_mfma, dim3(512), dim3(512), 0, stream,
                       cls_cl, reg_cl, wtcf, wtrf, pts, dc_cls, dc_reg, stats);
    hipLaunchKernelGGL(gn_relu_nchw, dim3(2048, 2), dim3(256), 0, stream,
                       dc_cls, dc_reg, out_cls, out_reg,
                       stats, cls_g, cls_bt, reg_g, reg_bt);
}